// Round 13
// baseline (241.510 us; speedup 1.0000x reference)
//
#include <hip/hip_runtime.h>

typedef __bf16 bf16x8 __attribute__((ext_vector_type(8)));
typedef float f32x4 __attribute__((ext_vector_type(4)));

typedef const unsigned int __attribute__((address_space(1)))* gas_p;
typedef unsigned int __attribute__((address_space(3)))* las_p;

__device__ __forceinline__ void gload_lds16(const void* g, void* l) {
  __builtin_amdgcn_global_load_lds((gas_p)g, (las_p)l, 16, 0, 0);
}

__device__ __forceinline__ unsigned short f2bf(float f) {
  union { float f; unsigned int u; } x; x.f = f;
  unsigned int r = x.u + 0x7fffu + ((x.u >> 16) & 1u);
  return (unsigned short)(r >> 16);
}
__device__ __forceinline__ float elu1(float x) {
  return x > 0.f ? x + 1.f : __expf(x);
}
__device__ __forceinline__ f32x4 mfma16(bf16x8 a, bf16x8 b, f32x4 c) {
  return __builtin_amdgcn_mfma_f32_16x16x32_bf16(a, b, c, 0, 0, 0);
}

#define BAR() __builtin_amdgcn_s_barrier()
#define VMW0() asm volatile("s_waitcnt vmcnt(0)" ::: "memory")

// ---------------- converts ----------------

__global__ __launch_bounds__(256) void k_cvt_x(const float* __restrict__ x,
                                               unsigned short* __restrict__ xb, int n) {
  int i = (blockIdx.x * 256 + threadIdx.x) * 4;
  const int stride = gridDim.x * 256 * 4;
  for (; i < n; i += stride) {
    float4 v = *(const float4*)(x + i);
    union { unsigned short u[4]; uint2 q; } pk;
    pk.u[0] = f2bf(v.x); pk.u[1] = f2bf(v.y); pk.u[2] = f2bf(v.z); pk.u[3] = f2bf(v.w);
    *(uint2*)(xb + i) = pk.q;
  }
}

// merged weight transposes: bx<96 -> w_qkv [1024][3072] -> wqkvT [3072][1024];
// bx>=96 -> w_proj [1024][1024] -> wprojT [1024][1024].
__global__ __launch_bounds__(256) void k_cvt_t2(const float* __restrict__ wq,
                                                unsigned short* __restrict__ wqT,
                                                const float* __restrict__ wp,
                                                unsigned short* __restrict__ wpT) {
  __shared__ float t[32][33];
  const int bx = blockIdx.x;
  const float* w = (bx < 96) ? wq : wp;
  unsigned short* wT = (bx < 96) ? wqT : wpT;
  const int Cc = (bx < 96) ? 3072 : 1024;
  const int j0 = ((bx < 96) ? bx : bx - 96) * 32, i0 = blockIdx.y * 32;
  const int tx = threadIdx.x & 31, ty = threadIdx.x >> 5;
#pragma unroll
  for (int k = 0; k < 4; ++k)
    t[ty + 8 * k][tx] = w[(size_t)(i0 + ty + 8 * k) * Cc + j0 + tx];
  __syncthreads();
#pragma unroll
  for (int k = 0; k < 4; ++k)
    wT[(size_t)(j0 + ty + 8 * k) * 1024 + i0 + tx] = f2bf(t[tx][ty + 8 * k]);
}

// ---------------- 128x128 GEMM, m97 structure: BK=32, 16 KiB LDS, 3 blocks/CU --------
// 256 thr = 4 waves (2wm x 2wn), wave tile 64x64, acc[4][4]. Single-buffered LDS
// [128][32] bf16 per operand; per K-step: BAR; stage (4 DMA); VMW0; BAR; 8 ds_read;
// 16 MFMA. Cross-BLOCK TLP (3 resident) overlaps pipes (m114/m97 mechanism).
// Swizzle: 16B q-window ^= (row&3); DMA source col pre-swizzled (rule 21).

template <int EPI>
__global__ __launch_bounds__(256, 3) void k_gemm128(
    const unsigned short* __restrict__ A, const unsigned short* __restrict__ BT, int NBX,
    unsigned short* __restrict__ qb, unsigned short* __restrict__ kT,
    unsigned short* __restrict__ vT, const float* __restrict__ bias,
    float* __restrict__ out) {
  __shared__ unsigned short Asb[128 * 32];
  __shared__ unsigned short Bsb[128 * 32];

  const int tid = threadIdx.x, lane = tid & 63, wave = tid >> 6;
  const int wm = wave >> 1, wn = wave & 1;
  int bid = blockIdx.x;
  { const int cpx = (int)gridDim.x >> 3; bid = (bid & 7) * cpx + (bid >> 3); }
  const int bx = bid % NBX, by = bid / NBX;
  const size_t bm0 = (size_t)by << 7, bn0 = (size_t)bx << 7;

  // staging: load l in {0,1}: row = (l*4+wave)*16 + (lane>>2), col16B-block = lane&3.
  // source block pre-swizzled: blk ^ (row&3), row&3 = (lane>>2)&3.
  const int srow = (wave << 4) + (lane >> 2);
  const int scol = (((lane & 3) ^ ((lane >> 2) & 3)) << 3);
  const unsigned short* Ag = A + (bm0 + srow) * 1024 + scol;
  const unsigned short* Bg = BT + (bn0 + srow) * 1024 + scol;
  unsigned short* Al = Asb + (wave << 9) + (lane << 3);
  unsigned short* Bl = Bsb + (wave << 9) + (lane << 3);

  // fragment reads: row r = *+lane&15; swizzled 16B window = (lane>>4) ^ (lane&3)
  const int qsw = (((lane >> 4) ^ (lane & 3)) << 3);
  const int arow = (wm << 6) + (lane & 15);
  const int brow = (wn << 6) + (lane & 15);

  f32x4 acc[4][4] = {};

  for (int ks = 0; ks < 1024; ks += 32) {
    BAR();  // all prev-step reads consumed
    gload_lds16(Ag + ks, Al);
    gload_lds16(Ag + 64 * 1024 + ks, Al + 2048);
    gload_lds16(Bg + ks, Bl);
    gload_lds16(Bg + 64 * 1024 + ks, Bl + 2048);
    VMW0();
    BAR();  // publish
    bf16x8 a[4], b[4];
#pragma unroll
    for (int m = 0; m < 4; ++m)
      a[m] = *(const bf16x8*)&Asb[((arow + m * 16) << 5) + qsw];
#pragma unroll
    for (int n = 0; n < 4; ++n)
      b[n] = *(const bf16x8*)&Bsb[((brow + n * 16) << 5) + qsw];
    __builtin_amdgcn_s_setprio(1);
#pragma unroll
    for (int m = 0; m < 4; ++m)
#pragma unroll
      for (int n = 0; n < 4; ++n) acc[m][n] = mfma16(a[m], b[n], acc[m][n]);
    __builtin_amdgcn_s_setprio(0);
  }

  // ---- epilogue ----
  const int rbase = (int)bm0 + (wm << 6) + ((lane >> 4) << 2);
  const int cbase = (int)bn0 + (wn << 6) + (lane & 15);
  if constexpr (EPI == 0) {
    const int reg3 = (int)(bn0 >> 10);  // 0=q 1=k 2=v, uniform per block
#pragma unroll
    for (int m = 0; m < 4; ++m) {
      const int rb = rbase + m * 16;
#pragma unroll
      for (int n = 0; n < 4; ++n) {
        const int col = cbase + n * 16;
        if (reg3 == 0) {
#pragma unroll
          for (int i = 0; i < 4; ++i)
            qb[(size_t)(rb + i) * 1024 + col] = f2bf(elu1(acc[m][n][i]));
        } else {
          const int jc = col & 1023, h = jc >> 6, d = jc & 63;
          const int b_ = rb >> 12, n_ = rb & 4095;
          union { unsigned short u[4]; uint2 q; } pk;
          if (reg3 == 1) {
#pragma unroll
            for (int i = 0; i < 4; ++i) pk.u[i] = f2bf(elu1(acc[m][n][i]));
          } else {
#pragma unroll
            for (int i = 0; i < 4; ++i) pk.u[i] = f2bf(acc[m][n][i]);
          }
          unsigned short* dst = (reg3 == 1) ? kT : vT;
          *(uint2*)(dst + ((size_t)((b_ * 16 + h) * 64 + d) * 4096 + n_)) = pk.q;
        }
      }
    }
  } else {
#pragma unroll
    for (int n = 0; n < 4; ++n) {
      const int col = cbase + n * 16;
      const float bc = bias[col];
#pragma unroll
      for (int m = 0; m < 4; ++m) {
        const int rb = rbase + m * 16;
#pragma unroll
        for (int i = 0; i < 4; ++i)
          out[(size_t)(rb + i) * 1024 + col] = acc[m][n][i] + bc;
      }
    }
  }
}

// ---------------- kv partial (+ fused sum_k via ones-column) ----------------

__global__ __launch_bounds__(256) void k_kvpart(const unsigned short* __restrict__ kT,
                                                const unsigned short* __restrict__ vT,
                                                float* __restrict__ kvp,
                                                float* __restrict__ sumkp) {
  __shared__ unsigned short Ks[64 * 64];
  __shared__ unsigned short Vs[64 * 64];
  const int blk = blockIdx.x;
  const int bh = blk >> 3, ch = blk & 7;
  const int tid = threadIdx.x, lane = tid & 63, wave = tid >> 6;
  const unsigned short* kb = kT + (size_t)bh * 64 * 4096;
  const unsigned short* vb = vT + (size_t)bh * 64 * 4096;
  const int n0 = ch * 512;
  const int lrow = lane >> 3;
  const int lcolz = (((lane & 7) ^ (lane >> 3)) << 3);
  f32x4 acc[5] = {};

  bf16x8 ones_frag;
  {
    unsigned short o = ((lane & 15) == 0) ? (unsigned short)0x3F80 : (unsigned short)0;
    union { unsigned short u[8]; bf16x8 v; } c;
#pragma unroll
    for (int i = 0; i < 8; ++i) c.u[i] = o;
    ones_frag = c.v;
  }

  const int rxor = (lane & 7) << 3;
  const int col0 = (((lane >> 4) << 3)) ^ rxor;
  const int col1 = ((32 + ((lane >> 4) << 3))) ^ rxor;

  for (int ks = 0; ks < 512; ks += 64) {
    __syncthreads();
#pragma unroll
    for (int i = 0; i < 2; ++i) {
      const int c = i * 4 + wave;
      gload_lds16(kb + (size_t)(c * 8 + lrow) * 4096 + n0 + ks + lcolz, &Ks[c * 512]);
      gload_lds16(vb + (size_t)(c * 8 + lrow) * 4096 + n0 + ks + lcolz, &Vs[c * 512]);
    }
    __syncthreads();
    const int ar = wave * 16 + (lane & 15);
#pragma unroll
    for (int kk = 0; kk < 2; ++kk) {
      const int co = kk ? col1 : col0;
      bf16x8 a = *(const bf16x8*)&Ks[ar * 64 + co];
#pragma unroll
      for (int n = 0; n < 4; ++n) {
        bf16x8 bv = *(const bf16x8*)&Vs[(n * 16 + (lane & 15)) * 64 + co];
        acc[n] = mfma16(a, bv, acc[n]);
      }
      acc[4] = mfma16(a, ones_frag, acc[4]);
    }
  }
  float* dst = kvp + (size_t)blk * 64 * 64;
  const int d0 = wave * 16 + ((lane >> 4) << 2);
#pragma unroll
  for (int n = 0; n < 4; ++n)
#pragma unroll
    for (int i = 0; i < 4; ++i)
      dst[(d0 + i) * 64 + n * 16 + (lane & 15)] = acc[n][i];
  if ((lane & 15) == 0) {
#pragma unroll
    for (int i = 0; i < 4; ++i) sumkp[(size_t)blk * 64 + d0 + i] = acc[4][i];
  }
}

// ---------------- kv reduce ----------------

__global__ __launch_bounds__(256) void k_kvred(const float* __restrict__ kvp,
                                               const float* __restrict__ sumkp,
                                               unsigned short* __restrict__ kvsk) {
  const int bh = blockIdx.x, tid = threadIdx.x;
  const float* src = kvp + (size_t)bh * 8 * 4096;
  unsigned short* dst = kvsk + (size_t)bh * 80 * 64;
#pragma unroll
  for (int it = 0; it < 16; ++it) {
    const int idx = tid + it * 256;
    const int e = idx >> 6, d = idx & 63;
    float s = 0.f;
#pragma unroll
    for (int c = 0; c < 8; ++c) s += src[c * 4096 + d * 64 + e];
    dst[idx] = f2bf(s);
  }
#pragma unroll
  for (int it = 0; it < 4; ++it) {
    const int idx = tid + it * 256;
    const int e2 = idx >> 6, d = idx & 63;
    float v = 0.f;
    if (e2 == 0) {
#pragma unroll
      for (int c = 0; c < 8; ++c) v += sumkp[(size_t)(bh * 8 + c) * 64 + d];
    }
    dst[64 * 64 + idx] = f2bf(v);
  }
}

// ---------------- numerator/denominator/divide ----------------

__global__ __launch_bounds__(256) void k_numer(const unsigned short* __restrict__ qb,
                                               const unsigned short* __restrict__ kvsk,
                                               unsigned short* __restrict__ yb) {
  __shared__ unsigned short Bs[80 * 64];
  const int bh = blockIdx.y;
  const int b = bh >> 4, h = bh & 15;
  const int n0 = blockIdx.x << 7;
  const int tid = threadIdx.x, lane = tid & 63, wave = tid >> 6;
  {
    const uint4* src = (const uint4*)(kvsk + (size_t)bh * 80 * 64);
    uint4* dst = (uint4*)Bs;
    for (int i = tid; i < 640; i += 256) dst[i ^ ((i >> 3) & 7)] = src[i];
  }
  __syncthreads();

  const int ko = (lane >> 4) << 3;
  const int rx = (lane & 7) << 3;
  f32x4 acc[2][5] = {};
  const unsigned short* qrow =
      qb + (size_t)(b * 4096 + n0 + wave * 32 + (lane & 15)) * 1024 + h * 64;
#pragma unroll
  for (int kk = 0; kk < 2; ++kk) {
    bf16x8 a[2], bb[5];
#pragma unroll
    for (int m = 0; m < 2; ++m)
      a[m] = *(const bf16x8*)(qrow + (size_t)m * 16 * 1024 + ko + kk * 32);
#pragma unroll
    for (int n = 0; n < 5; ++n)
      bb[n] = *(const bf16x8*)&Bs[(n * 16 + (lane & 15)) * 64 + ((ko + kk * 32) ^ rx)];
#pragma unroll
    for (int m = 0; m < 2; ++m)
#pragma unroll
      for (int n = 0; n < 5; ++n)
        acc[m][n] = mfma16(a[m], bb[n], acc[m][n]);
  }

  const int rbase = b * 4096 + n0 + wave * 32 + ((lane >> 4) << 2);
#pragma unroll
  for (int m = 0; m < 2; ++m) {
    f32x4 inv;
#pragma unroll
    for (int i = 0; i < 4; ++i) {
      float den = __shfl(acc[m][4][i], lane & 48);
      inv[i] = __builtin_amdgcn_rcpf(den);
    }
#pragma unroll
    for (int n = 0; n < 4; ++n) {
      const int col = h * 64 + n * 16 + (lane & 15);
#pragma unroll
      for (int i = 0; i < 4; ++i)
        yb[(size_t)(rbase + m * 16 + i) * 1024 + col] = f2bf(acc[m][n][i] * inv[i]);
    }
  }
}

// ---------------- launch ----------------

extern "C" void kernel_launch(void* const* d_in, const int* in_sizes, int n_in,
                              void* d_out, int out_size, void* d_ws, size_t ws_size,
                              hipStream_t stream) {
  const float* x = (const float*)d_in[0];
  const float* w_qkv = (const float*)d_in[1];
  const float* w_proj = (const float*)d_in[2];
  const float* b_proj = (const float*)d_in[3];
  float* out = (float*)d_out;
  char* ws = (char*)d_ws;

  unsigned short* xb = (unsigned short*)(ws);                   // 33,554,432 B (reused as yb)
  unsigned short* wqkvT = (unsigned short*)(ws + 33554432);     //  6,291,456 B (reused as sumkp)
  unsigned short* wprojT = (unsigned short*)(ws + 39845888);    //  2,097,152 B
  unsigned short* qb = (unsigned short*)(ws + 41943040);        // 33,554,432 B
  unsigned short* kT = (unsigned short*)(ws + 75497472);        // 33,554,432 B
  unsigned short* vT = (unsigned short*)(ws + 109051904);       // 33,554,432 B
  float* kvp = (float*)(ws + 142606336);                        //  8,388,608 B
  unsigned short* kvsk = (unsigned short*)(ws + 151011328);     //    655,360 B
  unsigned short* yb = xb;                 // xb dead after GEMM1
  float* sumkp = (float*)wqkvT;            // wqkvT dead after GEMM1 (512*64*4 B)

  k_cvt_x<<<2048, 256, 0, stream>>>(x, xb, 4 * 4096 * 1024);
  k_cvt_t2<<<dim3(128, 32), 256, 0, stream>>>(w_qkv, wqkvT, w_proj, wprojT);
  k_gemm128<0><<<3072, 256, 0, stream>>>(xb, wqkvT, 24, qb, kT, vT, nullptr, nullptr);
  k_kvpart<<<512, 256, 0, stream>>>(kT, vT, kvp, sumkp);
  k_kvred<<<64, 256, 0, stream>>>(kvp, sumkp, kvsk);
  k_numer<<<dim3(32, 64), 256, 0, stream>>>(qb, kvsk, yb);
  k_gemm128<1><<<1024, 256, 0, stream>>>(yb, wprojT, 8, nullptr, nullptr, nullptr,
                                         b_proj, out);
}

// Round 14
// 222.935 us; speedup vs baseline: 1.0833x; 1.0833x over previous
//
#include <hip/hip_runtime.h>

typedef __bf16 bf16x8 __attribute__((ext_vector_type(8)));
typedef float f32x4 __attribute__((ext_vector_type(4)));

typedef const unsigned int __attribute__((address_space(1)))* gas_p;
typedef unsigned int __attribute__((address_space(3)))* las_p;

__device__ __forceinline__ void gload_lds16(const void* g, void* l) {
  __builtin_amdgcn_global_load_lds((gas_p)g, (las_p)l, 16, 0, 0);
}

__device__ __forceinline__ unsigned short f2bf(float f) {
  union { float f; unsigned int u; } x; x.f = f;
  unsigned int r = x.u + 0x7fffu + ((x.u >> 16) & 1u);
  return (unsigned short)(r >> 16);
}
__device__ __forceinline__ float elu1(float x) {
  return x > 0.f ? x + 1.f : __expf(x);
}
__device__ __forceinline__ f32x4 mfma16(bf16x8 a, bf16x8 b, f32x4 c) {
  return __builtin_amdgcn_mfma_f32_16x16x32_bf16(a, b, c, 0, 0, 0);
}

#define BAR() __builtin_amdgcn_s_barrier()
#define SB0() __builtin_amdgcn_sched_barrier(0)
#define VMW8() asm volatile("s_waitcnt vmcnt(8)" ::: "memory")
#define VMW4() asm volatile("s_waitcnt vmcnt(4)" ::: "memory")
#define VMW0() asm volatile("s_waitcnt vmcnt(0)" ::: "memory")
#define LGKMW() asm volatile("s_waitcnt lgkmcnt(0)" ::: "memory")

// ---------------- converts ----------------

__global__ __launch_bounds__(256) void k_cvt_x(const float* __restrict__ x,
                                               unsigned short* __restrict__ xb, int n) {
  int i = (blockIdx.x * 256 + threadIdx.x) * 4;
  const int stride = gridDim.x * 256 * 4;
  for (; i < n; i += stride) {
    float4 v = *(const float4*)(x + i);
    union { unsigned short u[4]; uint2 q; } pk;
    pk.u[0] = f2bf(v.x); pk.u[1] = f2bf(v.y); pk.u[2] = f2bf(v.z); pk.u[3] = f2bf(v.w);
    *(uint2*)(xb + i) = pk.q;
  }
}

__global__ __launch_bounds__(256) void k_cvt_t2(const float* __restrict__ wq,
                                                unsigned short* __restrict__ wqT,
                                                const float* __restrict__ wp,
                                                unsigned short* __restrict__ wpT) {
  __shared__ float t[32][33];
  const int bx = blockIdx.x;
  const float* w = (bx < 96) ? wq : wp;
  unsigned short* wT = (bx < 96) ? wqT : wpT;
  const int Cc = (bx < 96) ? 3072 : 1024;
  const int j0 = ((bx < 96) ? bx : bx - 96) * 32, i0 = blockIdx.y * 32;
  const int tx = threadIdx.x & 31, ty = threadIdx.x >> 5;
#pragma unroll
  for (int k = 0; k < 4; ++k)
    t[ty + 8 * k][tx] = w[(size_t)(i0 + ty + 8 * k) * Cc + j0 + tx];
  __syncthreads();
#pragma unroll
  for (int k = 0; k < 4; ++k)
    wT[(size_t)(j0 + ty + 8 * k) * 1024 + i0 + tx] = f2bf(t[tx][ty + 8 * k]);
}

// ---------------- 256x256 GEMM, 4-phase m201 style + sched_barrier pinning ------------
// LDS: 4 pair-slots/operand of [256 rows][32 K] bf16. pair p = 2*tile+kk in slot p&3.
// Per phase: {frag ds_reads; SB0 (pin reads BEFORE barrier); 1 stage-unit;
// [vmcnt(8) ph1/ph3, never 0 mid-loop]; BAR; lgkmcnt(0); SB0 (no MFMA hoist);
// setprio1; 16 MFMA; setprio0; BAR}. SB0 prevents hipcc sinking ds_reads past the
// asm barrier (rule-18 cousin) which would de-pipeline the phase into lockstep.
// Swizzle: read col ^= ((row>>1)&3)<<3 elems; DMA source col pre-swizzled (rule 21).

template <int EPI>
__global__ __launch_bounds__(512, 2) void k_gemm256(
    const unsigned short* __restrict__ A, const unsigned short* __restrict__ BT, int NBX,
    unsigned short* __restrict__ qb, unsigned short* __restrict__ kT,
    unsigned short* __restrict__ vT, const float* __restrict__ bias,
    float* __restrict__ out) {
  extern __shared__ unsigned short lds[];
  unsigned short* Asb = lds;           // 4 slots x 8192 elems (64 KiB)
  unsigned short* Bsb = lds + 32768;   // 4 slots x 8192 elems (64 KiB)

  const int tid = threadIdx.x, lane = tid & 63, wave = tid >> 6;
  const int wm = wave >> 2, wn = wave & 3;
  int bid = blockIdx.x;
  { const int cpx = (int)gridDim.x >> 3; bid = (bid & 7) * cpx + (bid >> 3); }
  const int bx = bid % NBX, by = bid / NBX;
  const size_t bm0 = (size_t)by << 8, bn0 = (size_t)bx << 8;

  const int srow = (wave << 4) + (lane >> 2);
  const int gscol = ((lane & 3) << 3) ^ (((srow >> 1) & 3) << 3);
  const unsigned short* Ag0 = A + (bm0 + srow) * 1024 + gscol;
  const unsigned short* Bg0 = BT + (bn0 + srow) * 1024 + gscol;
  const int lws = wave << 9;

  auto stageA = [&](int pair) {
    const unsigned short* g_ = Ag0 + (pair << 5);
    unsigned short* l_ = Asb + ((pair & 3) << 13) + lws;
    gload_lds16(g_, l_);
    gload_lds16(g_ + 128 * 1024, l_ + 4096);
  };
  auto stageB = [&](int pair) {
    const unsigned short* g_ = Bg0 + (pair << 5);
    unsigned short* l_ = Bsb + ((pair & 3) << 13) + lws;
    gload_lds16(g_, l_);
    gload_lds16(g_ + 128 * 1024, l_ + 4096);
  };

  const int q8 = ((lane >> 4) << 3) ^ (((lane >> 1) & 3) << 3);
  const int ar_base = (wm << 7) + (lane & 15);
  const int br_base = (wn << 6) + (lane & 15);

  f32x4 acc[8][4] = {};  // [rh*4+mi][n]

  // prologue: stage pairs 0,1,2 in order; vmcnt(8) -> pair 0 landed; publish.
  stageA(0); stageB(0);
  stageA(1); stageB(1);
  stageA(2); stageB(2);
  VMW8();
  BAR();

#pragma unroll
  for (int t = 0; t < 16; ++t) {
    const int s0 = ((2 * t) & 3) << 13, s1 = ((2 * t + 1) & 3) << 13;
    bf16x8 fA[4], fB[4], gA[4];

    // ---- ph0: reads(s0: A rh0 + B); stage A(2t+3); BAR; lgkm; MFMA[0..3] ----
#pragma unroll
    for (int mi = 0; mi < 4; ++mi)
      fA[mi] = *(const bf16x8*)&Asb[s0 + ((ar_base + mi * 16) << 5) + q8];
#pragma unroll
    for (int n = 0; n < 4; ++n)
      fB[n] = *(const bf16x8*)&Bsb[s0 + ((br_base + n * 16) << 5) + q8];
    SB0();
    if (t <= 14) stageA(2 * t + 3);
    BAR();
    LGKMW();
    SB0();
    __builtin_amdgcn_s_setprio(1);
#pragma unroll
    for (int mi = 0; mi < 4; ++mi)
#pragma unroll
      for (int n = 0; n < 4; ++n) acc[mi][n] = mfma16(fA[mi], fB[n], acc[mi][n]);
    __builtin_amdgcn_s_setprio(0);
    BAR();

    // ---- ph1: reads(s0: A rh1); stage B(2t+3); vmcnt; BAR; lgkm; MFMA[4..7] ----
#pragma unroll
    for (int mi = 0; mi < 4; ++mi)
      gA[mi] = *(const bf16x8*)&Asb[s0 + ((ar_base + 64 + mi * 16) << 5) + q8];
    SB0();
    if (t <= 14) { stageB(2 * t + 3); VMW8(); } else { VMW0(); }
    BAR();
    LGKMW();
    SB0();
    __builtin_amdgcn_s_setprio(1);
#pragma unroll
    for (int mi = 0; mi < 4; ++mi)
#pragma unroll
      for (int n = 0; n < 4; ++n) acc[4 + mi][n] = mfma16(gA[mi], fB[n], acc[4 + mi][n]);
    __builtin_amdgcn_s_setprio(0);
    BAR();

    // ---- ph2: reads(s1: A rh0 + B); stage A(2t+4); BAR; lgkm; MFMA[0..3] ----
#pragma unroll
    for (int mi = 0; mi < 4; ++mi)
      fA[mi] = *(const bf16x8*)&Asb[s1 + ((ar_base + mi * 16) << 5) + q8];
#pragma unroll
    for (int n = 0; n < 4; ++n)
      fB[n] = *(const bf16x8*)&Bsb[s1 + ((br_base + n * 16) << 5) + q8];
    SB0();
    if (t <= 13) stageA(2 * t + 4);
    BAR();
    LGKMW();
    SB0();
    __builtin_amdgcn_s_setprio(1);
#pragma unroll
    for (int mi = 0; mi < 4; ++mi)
#pragma unroll
      for (int n = 0; n < 4; ++n) acc[mi][n] = mfma16(fA[mi], fB[n], acc[mi][n]);
    __builtin_amdgcn_s_setprio(0);
    BAR();

    // ---- ph3: reads(s1: A rh1); stage B(2t+4); vmcnt; BAR; lgkm; MFMA[4..7] ----
#pragma unroll
    for (int mi = 0; mi < 4; ++mi)
      gA[mi] = *(const bf16x8*)&Asb[s1 + ((ar_base + 64 + mi * 16) << 5) + q8];
    SB0();
    if (t <= 13) { stageB(2 * t + 4); VMW8(); }
    else if (t == 14) { VMW4(); }
    BAR();
    LGKMW();
    SB0();
    __builtin_amdgcn_s_setprio(1);
#pragma unroll
    for (int mi = 0; mi < 4; ++mi)
#pragma unroll
      for (int n = 0; n < 4; ++n) acc[4 + mi][n] = mfma16(gA[mi], fB[n], acc[4 + mi][n]);
    __builtin_amdgcn_s_setprio(0);
    BAR();
  }

  // ---- epilogue ----
  const int rbase = (int)bm0 + (wm << 7) + ((lane >> 4) << 2);
  const int cbase = (int)bn0 + (wn << 6) + (lane & 15);
  if constexpr (EPI == 0) {
    const int reg3 = (int)(bn0 >> 10);  // 0=q 1=k 2=v, uniform per block
#pragma unroll
    for (int m = 0; m < 8; ++m) {
      const int rb = rbase + m * 16;
#pragma unroll
      for (int n = 0; n < 4; ++n) {
        const int col = cbase + n * 16;
        if (reg3 == 0) {
#pragma unroll
          for (int i = 0; i < 4; ++i)
            qb[(size_t)(rb + i) * 1024 + col] = f2bf(elu1(acc[m][n][i]));
        } else {
          const int jc = col & 1023, h = jc >> 6, d = jc & 63;
          const int b_ = rb >> 12, n_ = rb & 4095;
          union { unsigned short u[4]; uint2 q; } pk;
          if (reg3 == 1) {
#pragma unroll
            for (int i = 0; i < 4; ++i) pk.u[i] = f2bf(elu1(acc[m][n][i]));
          } else {
#pragma unroll
            for (int i = 0; i < 4; ++i) pk.u[i] = f2bf(acc[m][n][i]);
          }
          unsigned short* dst = (reg3 == 1) ? kT : vT;
          *(uint2*)(dst + ((size_t)((b_ * 16 + h) * 64 + d) * 4096 + n_)) = pk.q;
        }
      }
    }
  } else {
#pragma unroll
    for (int n = 0; n < 4; ++n) {
      const int col = cbase + n * 16;
      const float bc = bias[col];
#pragma unroll
      for (int m = 0; m < 8; ++m) {
        const int rb = rbase + m * 16;
#pragma unroll
        for (int i = 0; i < 4; ++i)
          out[(size_t)(rb + i) * 1024 + col] = acc[m][n][i] + bc;
      }
    }
  }
}

// ---------------- kv partial: ring-2 double-buffer (+ fused sum_k) ----------------

__global__ __launch_bounds__(256) void k_kvpart(const unsigned short* __restrict__ kT,
                                                const unsigned short* __restrict__ vT,
                                                float* __restrict__ kvp,
                                                float* __restrict__ sumkp) {
  __shared__ unsigned short Ks[2][64 * 64];
  __shared__ unsigned short Vs[2][64 * 64];
  const int blk = blockIdx.x;
  const int bh = blk >> 3, ch = blk & 7;
  const int tid = threadIdx.x, lane = tid & 63, wave = tid >> 6;
  const unsigned short* kb = kT + (size_t)bh * 64 * 4096;
  const unsigned short* vb = vT + (size_t)bh * 64 * 4096;
  const int n0 = ch * 512;
  const int lrow = lane >> 3;
  const int lcolz = (((lane & 7) ^ (lane >> 3)) << 3);
  f32x4 acc[5] = {};

  auto stage = [&](int buf, int ks) {
#pragma unroll
    for (int i = 0; i < 2; ++i) {
      const int c = i * 4 + wave;
      gload_lds16(kb + (size_t)(c * 8 + lrow) * 4096 + n0 + ks + lcolz, &Ks[buf][c * 512]);
      gload_lds16(vb + (size_t)(c * 8 + lrow) * 4096 + n0 + ks + lcolz, &Vs[buf][c * 512]);
    }
  };

  bf16x8 ones_frag;
  {
    unsigned short o = ((lane & 15) == 0) ? (unsigned short)0x3F80 : (unsigned short)0;
    union { unsigned short u[8]; bf16x8 v; } c;
#pragma unroll
    for (int i = 0; i < 8; ++i) c.u[i] = o;
    ones_frag = c.v;
  }

  const int rxor = (lane & 7) << 3;
  const int col0 = (((lane >> 4) << 3)) ^ rxor;
  const int col1 = ((32 + ((lane >> 4) << 3))) ^ rxor;

  stage(0, 0);
  VMW0();
  BAR();

#pragma unroll
  for (int it = 0; it < 8; ++it) {
    const int buf = it & 1;
    if (it < 7) stage(buf ^ 1, (it + 1) * 64);
    const int ar = wave * 16 + (lane & 15);
#pragma unroll
    for (int kk = 0; kk < 2; ++kk) {
      const int co = kk ? col1 : col0;
      bf16x8 a = *(const bf16x8*)&Ks[buf][ar * 64 + co];
#pragma unroll
      for (int n = 0; n < 4; ++n) {
        bf16x8 bv = *(const bf16x8*)&Vs[buf][(n * 16 + (lane & 15)) * 64 + co];
        acc[n] = mfma16(a, bv, acc[n]);
      }
      acc[4] = mfma16(a, ones_frag, acc[4]);
    }
    if (it < 7) { VMW0(); }
    BAR();
  }

  float* dst = kvp + (size_t)blk * 64 * 64;
  const int d0 = wave * 16 + ((lane >> 4) << 2);
#pragma unroll
  for (int n = 0; n < 4; ++n)
#pragma unroll
    for (int i = 0; i < 4; ++i)
      dst[(d0 + i) * 64 + n * 16 + (lane & 15)] = acc[n][i];
  if ((lane & 15) == 0) {
#pragma unroll
    for (int i = 0; i < 4; ++i) sumkp[(size_t)blk * 64 + d0 + i] = acc[4][i];
  }
}

// ---------------- kv reduce ----------------

__global__ __launch_bounds__(256) void k_kvred(const float* __restrict__ kvp,
                                               const float* __restrict__ sumkp,
                                               unsigned short* __restrict__ kvsk) {
  const int bh = blockIdx.x, tid = threadIdx.x;
  const float* src = kvp + (size_t)bh * 8 * 4096;
  unsigned short* dst = kvsk + (size_t)bh * 80 * 64;
#pragma unroll
  for (int it = 0; it < 16; ++it) {
    const int idx = tid + it * 256;
    const int e = idx >> 6, d = idx & 63;
    float s = 0.f;
#pragma unroll
    for (int c = 0; c < 8; ++c) s += src[c * 4096 + d * 64 + e];
    dst[idx] = f2bf(s);
  }
#pragma unroll
  for (int it = 0; it < 4; ++it) {
    const int idx = tid + it * 256;
    const int e2 = idx >> 6, d = idx & 63;
    float v = 0.f;
    if (e2 == 0) {
#pragma unroll
      for (int c = 0; c < 8; ++c) v += sumkp[(size_t)(bh * 8 + c) * 64 + d];
    }
    dst[64 * 64 + idx] = f2bf(v);
  }
}

// ---------------- numerator/denominator/divide ----------------

__global__ __launch_bounds__(256) void k_numer(const unsigned short* __restrict__ qb,
                                               const unsigned short* __restrict__ kvsk,
                                               unsigned short* __restrict__ yb) {
  __shared__ unsigned short Bs[80 * 64];
  const int bh = blockIdx.y;
  const int b = bh >> 4, h = bh & 15;
  const int n0 = blockIdx.x << 7;
  const int tid = threadIdx.x, lane = tid & 63, wave = tid >> 6;
  {
    const uint4* src = (const uint4*)(kvsk + (size_t)bh * 80 * 64);
    uint4* dst = (uint4*)Bs;
    for (int i = tid; i < 640; i += 256) dst[i ^ ((i >> 3) & 7)] = src[i];
  }
  __syncthreads();

  const int ko = (lane >> 4) << 3;
  const int rx = (lane & 7) << 3;
  f32x4 acc[2][5] = {};
  const unsigned short* qrow =
      qb + (size_t)(b * 4096 + n0 + wave * 32 + (lane & 15)) * 1024 + h * 64;
#pragma unroll
  for (int kk = 0; kk < 2; ++kk) {
    bf16x8 a[2], bb[5];
#pragma unroll
    for (int m = 0; m < 2; ++m)
      a[m] = *(const bf16x8*)(qrow + (size_t)m * 16 * 1024 + ko + kk * 32);
#pragma unroll
    for (int n = 0; n < 5; ++n)
      bb[n] = *(const bf16x8*)&Bs[(n * 16 + (lane & 15)) * 64 + ((ko + kk * 32) ^ rx)];
#pragma unroll
    for (int m = 0; m < 2; ++m)
#pragma unroll
      for (int n = 0; n < 5; ++n)
        acc[m][n] = mfma16(a[m], bb[n], acc[m][n]);
  }

  const int rbase = b * 4096 + n0 + wave * 32 + ((lane >> 4) << 2);
#pragma unroll
  for (int m = 0; m < 2; ++m) {
    f32x4 inv;
#pragma unroll
    for (int i = 0; i < 4; ++i) {
      float den = __shfl(acc[m][4][i], lane & 48);
      inv[i] = __builtin_amdgcn_rcpf(den);
    }
#pragma unroll
    for (int n = 0; n < 4; ++n) {
      const int col = h * 64 + n * 16 + (lane & 15);
#pragma unroll
      for (int i = 0; i < 4; ++i)
        yb[(size_t)(rbase + m * 16 + i) * 1024 + col] = f2bf(acc[m][n][i] * inv[i]);
    }
  }
}

// ---------------- launch ----------------

extern "C" void kernel_launch(void* const* d_in, const int* in_sizes, int n_in,
                              void* d_out, int out_size, void* d_ws, size_t ws_size,
                              hipStream_t stream) {
  const float* x = (const float*)d_in[0];
  const float* w_qkv = (const float*)d_in[1];
  const float* w_proj = (const float*)d_in[2];
  const float* b_proj = (const float*)d_in[3];
  float* out = (float*)d_out;
  char* ws = (char*)d_ws;

  unsigned short* xb = (unsigned short*)(ws);                   // 33,554,432 B (reused as yb)
  unsigned short* wqkvT = (unsigned short*)(ws + 33554432);     //  6,291,456 B (reused as sumkp)
  unsigned short* wprojT = (unsigned short*)(ws + 39845888);    //  2,097,152 B
  unsigned short* qb = (unsigned short*)(ws + 41943040);        // 33,554,432 B
  unsigned short* kT = (unsigned short*)(ws + 75497472);        // 33,554,432 B
  unsigned short* vT = (unsigned short*)(ws + 109051904);       // 33,554,432 B
  float* kvp = (float*)(ws + 142606336);                        //  8,388,608 B
  unsigned short* kvsk = (unsigned short*)(ws + 151011328);     //    655,360 B
  unsigned short* yb = xb;                 // xb dead after GEMM1
  float* sumkp = (float*)wqkvT;            // wqkvT dead after GEMM1 (512*64*4 B)

  k_cvt_x<<<2048, 256, 0, stream>>>(x, xb, 4 * 4096 * 1024);
  k_cvt_t2<<<dim3(128, 32), 256, 0, stream>>>(w_qkv, wqkvT, w_proj, wprojT);
  k_gemm256<0><<<768, 512, 131072, stream>>>(xb, wqkvT, 12, qb, kT, vT, nullptr, nullptr);
  k_kvpart<<<512, 256, 0, stream>>>(kT, vT, kvp, sumkp);
  k_kvred<<<64, 256, 0, stream>>>(kvp, sumkp, kvsk);
  k_numer<<<dim3(32, 64), 256, 0, stream>>>(qb, kvsk, yb);
  k_gemm256<1><<<256, 512, 131072, stream>>>(yb, wprojT, 4, nullptr, nullptr, nullptr,
                                             b_proj, out);
}

// Round 15
// 220.047 us; speedup vs baseline: 1.0975x; 1.0131x over previous
//
#include <hip/hip_runtime.h>

typedef __bf16 bf16x8 __attribute__((ext_vector_type(8)));
typedef float f32x4 __attribute__((ext_vector_type(4)));

typedef const unsigned int __attribute__((address_space(1)))* gas_p;
typedef unsigned int __attribute__((address_space(3)))* las_p;

__device__ __forceinline__ void gload_lds16(const void* g, void* l) {
  __builtin_amdgcn_global_load_lds((gas_p)g, (las_p)l, 16, 0, 0);
}

__device__ __forceinline__ unsigned short f2bf(float f) {
  union { float f; unsigned int u; } x; x.f = f;
  unsigned int r = x.u + 0x7fffu + ((x.u >> 16) & 1u);
  return (unsigned short)(r >> 16);
}
__device__ __forceinline__ float elu1(float x) {
  return x > 0.f ? x + 1.f : __expf(x);
}
__device__ __forceinline__ f32x4 mfma16(bf16x8 a, bf16x8 b, f32x4 c) {
  return __builtin_amdgcn_mfma_f32_16x16x32_bf16(a, b, c, 0, 0, 0);
}

#define BAR() __builtin_amdgcn_s_barrier()
#define VMW8() asm volatile("s_waitcnt vmcnt(8)" ::: "memory")
#define VMW0() asm volatile("s_waitcnt vmcnt(0)" ::: "memory")
#define LGKM0() do { asm volatile("s_waitcnt lgkmcnt(0)" ::: "memory"); \
                     __builtin_amdgcn_sched_barrier(0); } while (0)

// ---------------- merged prep: x f32->bf16 convert + both weight transposes ----------
// bid < 2048: grid-stride convert of x (16.8M elems).
// bid >= 2048: one 32x32 transpose tile; t = bid-2048: bx = t%128 (96 wqkv + 32 wproj),
// by = t/128.

__global__ __launch_bounds__(256) void k_prep(const float* __restrict__ x,
                                              unsigned short* __restrict__ xb,
                                              const float* __restrict__ wq,
                                              unsigned short* __restrict__ wqT,
                                              const float* __restrict__ wp,
                                              unsigned short* __restrict__ wpT) {
  const int bid = blockIdx.x;
  if (bid < 2048) {
    const int n = 4 * 4096 * 1024;
    int i = (bid * 256 + (int)threadIdx.x) * 4;
    const int stride = 2048 * 256 * 4;
    for (; i < n; i += stride) {
      float4 v = *(const float4*)(x + i);
      union { unsigned short u[4]; uint2 q; } pk;
      pk.u[0] = f2bf(v.x); pk.u[1] = f2bf(v.y); pk.u[2] = f2bf(v.z); pk.u[3] = f2bf(v.w);
      *(uint2*)(xb + i) = pk.q;
    }
    return;
  }
  __shared__ float t[32][33];
  const int tt = bid - 2048;
  const int bx = tt & 127, by = tt >> 7;
  const float* w = (bx < 96) ? wq : wp;
  unsigned short* wT = (bx < 96) ? wqT : wpT;
  const int Cc = (bx < 96) ? 3072 : 1024;
  const int j0 = ((bx < 96) ? bx : bx - 96) * 32, i0 = by * 32;
  const int tx = threadIdx.x & 31, ty = threadIdx.x >> 5;
#pragma unroll
  for (int k = 0; k < 4; ++k)
    t[ty + 8 * k][tx] = w[(size_t)(i0 + ty + 8 * k) * Cc + j0 + tx];
  __syncthreads();
#pragma unroll
  for (int k = 0; k < 4; ++k)
    wT[(size_t)(j0 + ty + 8 * k) * 1024 + i0 + tx] = f2bf(t[tx][ty + 8 * k]);
}

// ---------------- 256x256 GEMM, register-prefetch pipeline (R12 base, no setprio) ----
// LDS: 4 pair-slots/operand of [256 rows][32 K] bf16. pair p = 2*tile+kk in slot p&3.
// Per iter t: stage pairs {2t+3,2t+4}; read kk1 frags ## MFMA(kk0, prefetched);
// read next tile kk0 frags ## MFMA(kk1); LGKM0; VMW0; BAR. One barrier per K-tile.
// setprio REMOVED: T5 is null-to-negative on lockstep structures (m190).
// Swizzle: read col ^= ((row>>1)&3)<<3 elems; DMA source col pre-swizzled (rule 21).

template <int EPI>
__global__ __launch_bounds__(512, 1) void k_gemm256(
    const unsigned short* __restrict__ A, const unsigned short* __restrict__ BT, int NBX,
    unsigned short* __restrict__ qb, unsigned short* __restrict__ kT,
    unsigned short* __restrict__ vT, const float* __restrict__ bias,
    float* __restrict__ out) {
  extern __shared__ unsigned short lds[];
  unsigned short* Asb = lds;           // 4 slots x 8192 elems (64 KiB)
  unsigned short* Bsb = lds + 32768;   // 4 slots x 8192 elems (64 KiB)

  const int tid = threadIdx.x, lane = tid & 63, wave = tid >> 6;
  const int wm = wave >> 2, wn = wave & 3;
  int bid = blockIdx.x;
  { const int cpx = (int)gridDim.x >> 3; bid = (bid & 7) * cpx + (bid >> 3); }
  const int bx = bid % NBX, by = bid / NBX;
  const size_t bm0 = (size_t)by << 8, bn0 = (size_t)bx << 8;

  const int srow = (wave << 4) + (lane >> 2);
  const int gscol = ((lane & 3) << 3) ^ (((srow >> 1) & 3) << 3);
  const unsigned short* Ag0 = A + (bm0 + srow) * 1024 + gscol;
  const unsigned short* Bg0 = BT + (bn0 + srow) * 1024 + gscol;
  const int lws = wave << 9;

  auto stageA = [&](int pair) {
    const unsigned short* g_ = Ag0 + (pair << 5);
    unsigned short* l_ = Asb + ((pair & 3) << 13) + lws;
    gload_lds16(g_, l_);
    gload_lds16(g_ + 128 * 1024, l_ + 4096);
  };
  auto stageB = [&](int pair) {
    const unsigned short* g_ = Bg0 + (pair << 5);
    unsigned short* l_ = Bsb + ((pair & 3) << 13) + lws;
    gload_lds16(g_, l_);
    gload_lds16(g_ + 128 * 1024, l_ + 4096);
  };

  const int q8 = ((lane >> 4) << 3) ^ (((lane >> 1) & 3) << 3);
  const int ar_base = (wm << 7) + (lane & 15);
  const int br_base = (wn << 6) + (lane & 15);

  auto rdA = [&](int slot, int m) {
    return *(const bf16x8*)&Asb[(slot << 13) + ((ar_base + m * 16) << 5) + q8];
  };
  auto rdB = [&](int slot, int n) {
    return *(const bf16x8*)&Bsb[(slot << 13) + ((br_base + n * 16) << 5) + q8];
  };

  f32x4 acc[8][4] = {};   // [m][n]
  bf16x8 fA0[8], fB0[4];  // kk0 frags of current tile (prefetched)

  // prologue: stage pairs 0,1,2; publish pair 0; load its frags; publish pairs 1,2
  stageA(0); stageB(0);
  stageA(1); stageB(1);
  stageA(2); stageB(2);
  VMW8();   // pair 0 landed (own)
  BAR();    // pair 0 published
#pragma unroll
  for (int m = 0; m < 8; ++m) fA0[m] = rdA(0, m);
#pragma unroll
  for (int n = 0; n < 4; ++n) fB0[n] = rdB(0, n);
  LGKM0();  // pair-0 reads done (slot 0 overwritten at iter 0)
  VMW0();   // pairs 1,2 landed
  BAR();    // published

#pragma unroll
  for (int t = 0; t < 16; ++t) {
    const int s1 = (2 * t + 1) & 3, s2 = (2 * t + 2) & 3;

    // stage two pairs ahead (slots freed >=1 barrier ago)
    if (t <= 14) { stageA(2 * t + 3); stageB(2 * t + 3); }
    if (t <= 13) { stageA(2 * t + 4); stageB(2 * t + 4); }

    // read kk1 frags; MFMA kk0 (no dependency -> overlap in-wave)
    bf16x8 fA1[8], fB1[4];
#pragma unroll
    for (int m = 0; m < 8; ++m) fA1[m] = rdA(s1, m);
#pragma unroll
    for (int n = 0; n < 4; ++n) fB1[n] = rdB(s1, n);
#pragma unroll
    for (int m = 0; m < 8; ++m)
#pragma unroll
      for (int n = 0; n < 4; ++n) acc[m][n] = mfma16(fA0[m], fB0[n], acc[m][n]);

    // prefetch next tile's kk0 frags; MFMA kk1
    if (t <= 14) {
#pragma unroll
      for (int m = 0; m < 8; ++m) fA0[m] = rdA(s2, m);
#pragma unroll
      for (int n = 0; n < 4; ++n) fB0[n] = rdB(s2, n);
    }
#pragma unroll
    for (int m = 0; m < 8; ++m)
#pragma unroll
      for (int n = 0; n < 4; ++n) acc[m][n] = mfma16(fA1[m], fB1[n], acc[m][n]);

    if (t <= 14) {
      LGKM0();  // all own ds_reads complete (slots s1,s2 overwritten next iter)
      VMW0();   // this iter's DMA landed (in flight ~1 body)
      BAR();    // publish staged pairs; confirm reads block-wide
    }
  }

  // ---- epilogue ----
  const int rbase = (int)bm0 + (wm << 7) + ((lane >> 4) << 2);
  const int cbase = (int)bn0 + (wn << 6) + (lane & 15);
  if constexpr (EPI == 0) {
    const int reg3 = (int)(bn0 >> 10);  // 0=q 1=k 2=v, uniform per block
#pragma unroll
    for (int m = 0; m < 8; ++m) {
      const int rb = rbase + m * 16;
#pragma unroll
      for (int n = 0; n < 4; ++n) {
        const int col = cbase + n * 16;
        if (reg3 == 0) {
#pragma unroll
          for (int i = 0; i < 4; ++i)
            qb[(size_t)(rb + i) * 1024 + col] = f2bf(elu1(acc[m][n][i]));
        } else {
          const int jc = col & 1023, h = jc >> 6, d = jc & 63;
          const int b_ = rb >> 12, n_ = rb & 4095;
          union { unsigned short u[4]; uint2 q; } pk;
          if (reg3 == 1) {
#pragma unroll
            for (int i = 0; i < 4; ++i) pk.u[i] = f2bf(elu1(acc[m][n][i]));
          } else {
#pragma unroll
            for (int i = 0; i < 4; ++i) pk.u[i] = f2bf(acc[m][n][i]);
          }
          unsigned short* dst = (reg3 == 1) ? kT : vT;
          *(uint2*)(dst + ((size_t)((b_ * 16 + h) * 64 + d) * 4096 + n_)) = pk.q;
        }
      }
    }
  } else {
#pragma unroll
    for (int n = 0; n < 4; ++n) {
      const int col = cbase + n * 16;
      const float bc = bias[col];
#pragma unroll
      for (int m = 0; m < 8; ++m) {
        const int rb = rbase + m * 16;
#pragma unroll
        for (int i = 0; i < 4; ++i)
          out[(size_t)(rb + i) * 1024 + col] = acc[m][n][i] + bc;
      }
    }
  }
}

// ---------------- kv partial (+ fused sum_k via ones-column) ----------------

__global__ __launch_bounds__(256) void k_kvpart(const unsigned short* __restrict__ kT,
                                                const unsigned short* __restrict__ vT,
                                                float* __restrict__ kvp,
                                                float* __restrict__ sumkp) {
  __shared__ unsigned short Ks[64 * 64];
  __shared__ unsigned short Vs[64 * 64];
  const int blk = blockIdx.x;
  const int bh = blk >> 3, ch = blk & 7;
  const int tid = threadIdx.x, lane = tid & 63, wave = tid >> 6;
  const unsigned short* kb = kT + (size_t)bh * 64 * 4096;
  const unsigned short* vb = vT + (size_t)bh * 64 * 4096;
  const int n0 = ch * 512;
  const int lrow = lane >> 3;
  const int lcolz = (((lane & 7) ^ (lane >> 3)) << 3);
  f32x4 acc[5] = {};

  bf16x8 ones_frag;
  {
    unsigned short o = ((lane & 15) == 0) ? (unsigned short)0x3F80 : (unsigned short)0;
    union { unsigned short u[8]; bf16x8 v; } c;
#pragma unroll
    for (int i = 0; i < 8; ++i) c.u[i] = o;
    ones_frag = c.v;
  }

  const int rxor = (lane & 7) << 3;
  const int col0 = (((lane >> 4) << 3)) ^ rxor;
  const int col1 = ((32 + ((lane >> 4) << 3))) ^ rxor;

  for (int ks = 0; ks < 512; ks += 64) {
    __syncthreads();
#pragma unroll
    for (int i = 0; i < 2; ++i) {
      const int c = i * 4 + wave;
      gload_lds16(kb + (size_t)(c * 8 + lrow) * 4096 + n0 + ks + lcolz, &Ks[c * 512]);
      gload_lds16(vb + (size_t)(c * 8 + lrow) * 4096 + n0 + ks + lcolz, &Vs[c * 512]);
    }
    __syncthreads();
    const int ar = wave * 16 + (lane & 15);
#pragma unroll
    for (int kk = 0; kk < 2; ++kk) {
      const int co = kk ? col1 : col0;
      bf16x8 a = *(const bf16x8*)&Ks[ar * 64 + co];
#pragma unroll
      for (int n = 0; n < 4; ++n) {
        bf16x8 bv = *(const bf16x8*)&Vs[(n * 16 + (lane & 15)) * 64 + co];
        acc[n] = mfma16(a, bv, acc[n]);
      }
      acc[4] = mfma16(a, ones_frag, acc[4]);
    }
  }
  float* dst = kvp + (size_t)blk * 64 * 64;
  const int d0 = wave * 16 + ((lane >> 4) << 2);
#pragma unroll
  for (int n = 0; n < 4; ++n)
#pragma unroll
    for (int i = 0; i < 4; ++i)
      dst[(d0 + i) * 64 + n * 16 + (lane & 15)] = acc[n][i];
  if ((lane & 15) == 0) {
#pragma unroll
    for (int i = 0; i < 4; ++i) sumkp[(size_t)blk * 64 + d0 + i] = acc[4][i];
  }
}

// ---------------- kv reduce ----------------

__global__ __launch_bounds__(256) void k_kvred(const float* __restrict__ kvp,
                                               const float* __restrict__ sumkp,
                                               unsigned short* __restrict__ kvsk) {
  const int bh = blockIdx.x, tid = threadIdx.x;
  const float* src = kvp + (size_t)bh * 8 * 4096;
  unsigned short* dst = kvsk + (size_t)bh * 80 * 64;
#pragma unroll
  for (int it = 0; it < 16; ++it) {
    const int idx = tid + it * 256;
    const int e = idx >> 6, d = idx & 63;
    float s = 0.f;
#pragma unroll
    for (int c = 0; c < 8; ++c) s += src[c * 4096 + d * 64 + e];
    dst[idx] = f2bf(s);
  }
#pragma unroll
  for (int it = 0; it < 4; ++it) {
    const int idx = tid + it * 256;
    const int e2 = idx >> 6, d = idx & 63;
    float v = 0.f;
    if (e2 == 0) {
#pragma unroll
      for (int c = 0; c < 8; ++c) v += sumkp[(size_t)(bh * 8 + c) * 64 + d];
    }
    dst[64 * 64 + idx] = f2bf(v);
  }
}

// ---------------- numerator/denominator/divide ----------------

__global__ __launch_bounds__(256) void k_numer(const unsigned short* __restrict__ qb,
                                               const unsigned short* __restrict__ kvsk,
                                               unsigned short* __restrict__ yb) {
  __shared__ unsigned short Bs[80 * 64];
  const int bh = blockIdx.y;
  const int b = bh >> 4, h = bh & 15;
  const int n0 = blockIdx.x << 7;
  const int tid = threadIdx.x, lane = tid & 63, wave = tid >> 6;
  {
    const uint4* src = (const uint4*)(kvsk + (size_t)bh * 80 * 64);
    uint4* dst = (uint4*)Bs;
    for (int i = tid; i < 640; i += 256) dst[i ^ ((i >> 3) & 7)] = src[i];
  }
  __syncthreads();

  const int ko = (lane >> 4) << 3;
  const int rx = (lane & 7) << 3;
  f32x4 acc[2][5] = {};
  const unsigned short* qrow =
      qb + (size_t)(b * 4096 + n0 + wave * 32 + (lane & 15)) * 1024 + h * 64;
#pragma unroll
  for (int kk = 0; kk < 2; ++kk) {
    bf16x8 a[2], bb[5];
#pragma unroll
    for (int m = 0; m < 2; ++m)
      a[m] = *(const bf16x8*)(qrow + (size_t)m * 16 * 1024 + ko + kk * 32);
#pragma unroll
    for (int n = 0; n < 5; ++n)
      bb[n] = *(const bf16x8*)&Bs[(n * 16 + (lane & 15)) * 64 + ((ko + kk * 32) ^ rx)];
#pragma unroll
    for (int m = 0; m < 2; ++m)
#pragma unroll
      for (int n = 0; n < 5; ++n)
        acc[m][n] = mfma16(a[m], bb[n], acc[m][n]);
  }

  const int rbase = b * 4096 + n0 + wave * 32 + ((lane >> 4) << 2);
#pragma unroll
  for (int m = 0; m < 2; ++m) {
    f32x4 inv;
#pragma unroll
    for (int i = 0; i < 4; ++i) {
      float den = __shfl(acc[m][4][i], lane & 48);
      inv[i] = __builtin_amdgcn_rcpf(den);
    }
#pragma unroll
    for (int n = 0; n < 4; ++n) {
      const int col = h * 64 + n * 16 + (lane & 15);
#pragma unroll
      for (int i = 0; i < 4; ++i)
        yb[(size_t)(rbase + m * 16 + i) * 1024 + col] = f2bf(acc[m][n][i] * inv[i]);
    }
  }
}

// ---------------- launch ----------------

extern "C" void kernel_launch(void* const* d_in, const int* in_sizes, int n_in,
                              void* d_out, int out_size, void* d_ws, size_t ws_size,
                              hipStream_t stream) {
  const float* x = (const float*)d_in[0];
  const float* w_qkv = (const float*)d_in[1];
  const float* w_proj = (const float*)d_in[2];
  const float* b_proj = (const float*)d_in[3];
  float* out = (float*)d_out;
  char* ws = (char*)d_ws;

  unsigned short* xb = (unsigned short*)(ws);                   // 33,554,432 B (reused as yb)
  unsigned short* wqkvT = (unsigned short*)(ws + 33554432);     //  6,291,456 B (reused as sumkp)
  unsigned short* wprojT = (unsigned short*)(ws + 39845888);    //  2,097,152 B
  unsigned short* qb = (unsigned short*)(ws + 41943040);        // 33,554,432 B
  unsigned short* kT = (unsigned short*)(ws + 75497472);        // 33,554,432 B
  unsigned short* vT = (unsigned short*)(ws + 109051904);       // 33,554,432 B
  float* kvp = (float*)(ws + 142606336);                        //  8,388,608 B
  unsigned short* kvsk = (unsigned short*)(ws + 151011328);     //    655,360 B
  unsigned short* yb = xb;                 // xb dead after GEMM1
  float* sumkp = (float*)wqkvT;            // wqkvT dead after GEMM1 (512*64*4 B)

  k_prep<<<6144, 256, 0, stream>>>(x, xb, w_qkv, wqkvT, w_proj, wprojT);
  k_gemm256<0><<<768, 512, 131072, stream>>>(xb, wqkvT, 12, qb, kT, vT, nullptr, nullptr);
  k_kvpart<<<512, 256, 0, stream>>>(kT, vT, kvp, sumkp);
  k_kvred<<<64, 256, 0, stream>>>(kvp, sumkp, kvsk);
  k_numer<<<dim3(32, 64), 256, 0, stream>>>(qb, kvsk, yb);
  k_gemm256<1><<<256, 512, 131072, stream>>>(yb, wprojT, 4, nullptr, nullptr, nullptr,
                                             b_proj, out);
}